// Round 3
// baseline (1209.537 us; speedup 1.0000x reference)
//
#include <hip/hip_runtime.h>

#define DIM 64
#define BOT 15
#define NLAYERS 5
#define BN_EPS 1e-5f
#define ROWS 32
#define THREADS 256

// ---------------- CSR build ----------------

__global__ __launch_bounds__(256) void hist_k(const int* __restrict__ dst,
                                              int* __restrict__ deg, int E) {
    int e = blockIdx.x * blockDim.x + threadIdx.x;
    if (e < E) atomicAdd(&deg[dst[e]], 1);
}

// hierarchical scan: per-1024-block exclusive scan + block sums
__global__ __launch_bounds__(1024) void scan_part_k(const int* __restrict__ deg,
                                                    int* __restrict__ excl,
                                                    int* __restrict__ bsum, int n) {
    __shared__ int buf[1024];
    int t = threadIdx.x;
    int idx = blockIdx.x * 1024 + t;
    int v = (idx < n) ? deg[idx] : 0;
    buf[t] = v;
    __syncthreads();
    for (int off = 1; off < 1024; off <<= 1) {
        int x = (t >= off) ? buf[t - off] : 0;
        __syncthreads();
        buf[t] += x;
        __syncthreads();
    }
    if (idx < n) excl[idx] = buf[t] - v;
    if (t == 0) bsum[blockIdx.x] = buf[1023];
}

// scan the (<=1024) block sums; also writes row_ptr[n] = total
__global__ __launch_bounds__(1024) void scan_top_k(const int* __restrict__ bsum,
                                                   int* __restrict__ boff, int nb,
                                                   int* __restrict__ row_ptr, int n) {
    __shared__ int buf[1024];
    int t = threadIdx.x;
    int v = (t < nb) ? bsum[t] : 0;
    buf[t] = v;
    __syncthreads();
    for (int off = 1; off < 1024; off <<= 1) {
        int x = (t >= off) ? buf[t - off] : 0;
        __syncthreads();
        buf[t] += x;
        __syncthreads();
    }
    if (t < nb) boff[t] = buf[t] - v;
    if (t == 1023) row_ptr[n] = buf[1023];
}

// add block offsets; copy into deg as the scatter cursor
__global__ __launch_bounds__(256) void scan_add_k(int* __restrict__ row_ptr,
                                                  const int* __restrict__ boff,
                                                  int* __restrict__ deg, int n) {
    int i = blockIdx.x * blockDim.x + threadIdx.x;
    if (i < n) {
        int v = row_ptr[i] + boff[i >> 10];
        row_ptr[i] = v;
        deg[i] = v;
    }
}

__global__ __launch_bounds__(256) void scatter_k(const int* __restrict__ src,
                                                 const int* __restrict__ dst,
                                                 int* __restrict__ cursor,
                                                 int* __restrict__ csr, int E) {
    int e = blockIdx.x * blockDim.x + threadIdx.x;
    if (e < E) {
        int p = atomicAdd(&cursor[dst[e]], 1);
        csr[p] = src[e];
    }
}

// ---------------- fallback aggregation (small-ws path) ----------------

__global__ __launch_bounds__(256) void aggr_k(const float* __restrict__ h,
                                              const int* __restrict__ row_ptr,
                                              const int* __restrict__ csr,
                                              float* __restrict__ out, int n) {
    int gid = blockIdx.x * blockDim.x + threadIdx.x;
    int node = gid >> 6;
    int lane = gid & 63;
    if (node >= n) return;
    int s = row_ptr[node], e = row_ptr[node + 1];
    float acc = 0.f;
    int i = s;
    for (; i + 4 <= e; i += 4) {
        int a = csr[i], b = csr[i + 1], c = csr[i + 2], d = csr[i + 3];
        acc += (h[a * DIM + lane] + h[b * DIM + lane]) +
               (h[c * DIM + lane] + h[d * DIM + lane]);
    }
    for (; i < e; ++i) acc += h[csr[i] * DIM + lane];
    out[node * DIM + lane] = acc;
}

// ---------------- fast path: fused gather + GEMMs + stats + store y/u/v ----------

__global__ __launch_bounds__(THREADS) void fused_k(
    const float* __restrict__ h, const int* __restrict__ row_ptr,
    const int* __restrict__ csr,
    const float* __restrict__ Wc, const float* __restrict__ bc,
    const float* __restrict__ p1a, const float* __restrict__ b1a,
    const float* __restrict__ p2a, const float* __restrict__ b2a,
    const float* __restrict__ p1b, const float* __restrict__ b1b,
    const float* __restrict__ p2b, const float* __restrict__ b2b,
    float* __restrict__ partials,
    float* __restrict__ yv, float* __restrict__ uv, float* __restrict__ vv,
    int n) {
    __shared__ float xh[ROWS][DIM + 4];   // +4 pad keeps float4 alignment, shifts banks
    __shared__ float xa[ROWS][DIM + 4];
    __shared__ float m0[ROWS][17];
    __shared__ float m1[ROWS][17];
    __shared__ float red[6][4][DIM];

    int t = threadIdx.x;
    int rowBase = blockIdx.x * ROWS;

    // phase A1: stage 32 rows of h (float4, coalesced)
    #pragma unroll
    for (int i = 0; i < 2; i++) {
        int idx = t + i * 256;        // float4 index; 16 per row
        int r = idx >> 4, c4 = idx & 15;
        int gr = rowBase + r;
        float4 v = {0.f, 0.f, 0.f, 0.f};
        if (gr < n) v = *(const float4*)&h[(size_t)gr * DIM + c4 * 4];
        *(float4*)&xh[r][c4 * 4] = v;
    }

    // phase A2: CSR gather-sum directly into xa. wave per node, 4 neighbors/iter.
    {
        int wave = t >> 6, lane = t & 63;
        int j = lane >> 4, q = lane & 15;
        for (int rr = wave; rr < ROWS; rr += 4) {
            int gr = rowBase + rr;
            float4 acc = {0.f, 0.f, 0.f, 0.f};
            if (gr < n) {
                int s = row_ptr[gr], e = row_ptr[gr + 1];
                for (int i = s; i < e; i += 4) {
                    int ii = i + j;
                    if (ii < e) {
                        int idx = csr[ii];
                        float4 v = *(const float4*)&h[(size_t)idx * DIM + q * 4];
                        acc.x += v.x; acc.y += v.y; acc.z += v.z; acc.w += v.w;
                    }
                }
            }
            acc.x += __shfl_xor(acc.x, 16); acc.y += __shfl_xor(acc.y, 16);
            acc.z += __shfl_xor(acc.z, 16); acc.w += __shfl_xor(acc.w, 16);
            acc.x += __shfl_xor(acc.x, 32); acc.y += __shfl_xor(acc.y, 32);
            acc.z += __shfl_xor(acc.z, 32); acc.w += __shfl_xor(acc.w, 32);
            if (lane < 16) *(float4*)&xa[rr][q * 4] = acc;
        }
    }
    __syncthreads();

    // phase B: adapter bottleneck mids: relu(x @ w1 + b1)
    {
        int r = t >> 3, sub = t & 7;
        #pragma unroll
        for (int half = 0; half < 2; half++) {
            int m = sub + half * 8;
            if (m < BOT) {
                float s0 = b1a[m], s1 = b1b[m];
                #pragma unroll
                for (int k = 0; k < DIM; k++) {
                    s0 = fmaf(xh[r][k], p1a[k * BOT + m], s0);
                    s1 = fmaf(xa[r][k], p1b[k * BOT + m], s1);
                }
                m0[r][m] = fmaxf(s0, 0.f);
                m1[r][m] = fmaxf(s1, 0.f);
            }
        }
    }
    __syncthreads();

    // phase C: conv + adapter outputs, store y/u/v, accumulate stats
    int col = t & 63;
    int rg = t >> 6;
    float sums[6] = {0.f, 0.f, 0.f, 0.f, 0.f, 0.f};
    #pragma unroll
    for (int i = 0; i < ROWS / 4; i++) {
        int r = rg + i * 4;
        int gr = rowBase + r;
        float s = bc[col];
        #pragma unroll
        for (int k = 0; k < DIM; k++) s = fmaf(xa[r][k], Wc[k * DIM + col], s);
        float u = b2a[col];
        #pragma unroll
        for (int m = 0; m < BOT; m++) u = fmaf(m0[r][m], p2a[m * DIM + col], u);
        float v = b2b[col];
        #pragma unroll
        for (int m = 0; m < BOT; m++) v = fmaf(m1[r][m], p2b[m * DIM + col], v);
        if (gr < n) {
            size_t o = (size_t)gr * DIM + col;
            yv[o] = s; uv[o] = u; vv[o] = v;
            sums[0] += s; sums[1] += s * s;
            sums[2] += u; sums[3] += u * u;
            sums[4] += v; sums[5] += v * v;
        }
    }

    #pragma unroll
    for (int j = 0; j < 6; j++) red[j][rg][col] = sums[j];
    __syncthreads();
    if (t < DIM) {
        #pragma unroll
        for (int j = 0; j < 6; j++) {
            float v = red[j][0][t] + red[j][1][t] + red[j][2][t] + red[j][3][t];
            partials[((size_t)blockIdx.x * 6 + j) * DIM + t] = v;
        }
    }
}

// ---------------- elementwise apply (fast path pass 2) ----------------

template <int RELU>
__global__ __launch_bounds__(256) void apply_k(
    const float* __restrict__ yv, const float* __restrict__ uv,
    const float* __restrict__ vv, const float* __restrict__ ST,
    float* __restrict__ out, int n4) {
    int i = blockIdx.x * blockDim.x + threadIdx.x;   // float4 index
    if (i >= n4) return;
    int c4 = (i & 15) * 4;
    float4 S0 = *(const float4*)&ST[c4];
    float4 T0 = *(const float4*)&ST[64 + c4];
    float4 S1 = *(const float4*)&ST[128 + c4];
    float4 T1 = *(const float4*)&ST[192 + c4];
    float4 S2 = *(const float4*)&ST[256 + c4];
    float4 T2 = *(const float4*)&ST[320 + c4];
    float4 y = *(const float4*)&yv[(size_t)i * 4];
    float4 u = *(const float4*)&uv[(size_t)i * 4];
    float4 v = *(const float4*)&vv[(size_t)i * 4];
    float4 r;
    r.x = fmaf(y.x, S0.x, T0.x) + fmaf(u.x, S1.x, T1.x) + fmaf(v.x, S2.x, T2.x);
    r.y = fmaf(y.y, S0.y, T0.y) + fmaf(u.y, S1.y, T1.y) + fmaf(v.y, S2.y, T2.y);
    r.z = fmaf(y.z, S0.z, T0.z) + fmaf(u.z, S1.z, T1.z) + fmaf(v.z, S2.z, T2.z);
    r.w = fmaf(y.w, S0.w, T0.w) + fmaf(u.w, S1.w, T1.w) + fmaf(v.w, S2.w, T2.w);
    if (RELU) {
        r.x = fmaxf(r.x, 0.f); r.y = fmaxf(r.y, 0.f);
        r.z = fmaxf(r.z, 0.f); r.w = fmaxf(r.w, 0.f);
    }
    *(float4*)&out[(size_t)i * 4] = r;
}

// ---------------- fallback per-layer compute (small-ws path) ----------------

template <int MODE>  // 0: stats, 1: apply, 2: apply+relu
__global__ __launch_bounds__(THREADS) void layer_k(
    const float* __restrict__ h, const float* __restrict__ aggr,
    const float* __restrict__ Wc, const float* __restrict__ bc,
    const float* __restrict__ p1a, const float* __restrict__ b1a,
    const float* __restrict__ p2a, const float* __restrict__ b2a,
    const float* __restrict__ p1b, const float* __restrict__ b1b,
    const float* __restrict__ p2b, const float* __restrict__ b2b,
    float* __restrict__ partials, const float* __restrict__ ST,
    float* __restrict__ hout, int n) {
    __shared__ float xh[ROWS][DIM + 1];
    __shared__ float xa[ROWS][DIM + 1];
    __shared__ float m0[ROWS][17];
    __shared__ float m1[ROWS][17];
    __shared__ float red[6][4][DIM];

    int t = threadIdx.x;
    int rowBase = blockIdx.x * ROWS;

    #pragma unroll
    for (int i = 0; i < (ROWS * DIM) / THREADS; i++) {
        int idx = t + i * THREADS;
        int r = idx >> 6, c = idx & 63;
        int gr = rowBase + r;
        float vh = 0.f, va = 0.f;
        if (gr < n) { vh = h[(size_t)gr * DIM + c]; va = aggr[(size_t)gr * DIM + c]; }
        xh[r][c] = vh;
        xa[r][c] = va;
    }
    __syncthreads();

    {
        int r = t >> 3, sub = t & 7;
        #pragma unroll
        for (int half = 0; half < 2; half++) {
            int m = sub + half * 8;
            if (m < BOT) {
                float s0 = b1a[m], s1 = b1b[m];
                #pragma unroll
                for (int k = 0; k < DIM; k++) {
                    s0 = fmaf(xh[r][k], p1a[k * BOT + m], s0);
                    s1 = fmaf(xa[r][k], p1b[k * BOT + m], s1);
                }
                m0[r][m] = fmaxf(s0, 0.f);
                m1[r][m] = fmaxf(s1, 0.f);
            }
        }
    }
    __syncthreads();

    int col = t & 63;
    int rg = t >> 6;
    float sums[6] = {0.f, 0.f, 0.f, 0.f, 0.f, 0.f};
    float S0 = 0, T0 = 0, S1 = 0, T1 = 0, S2 = 0, T2 = 0;
    if (MODE != 0) {
        S0 = ST[col];        T0 = ST[64 + col];
        S1 = ST[128 + col];  T1 = ST[192 + col];
        S2 = ST[256 + col];  T2 = ST[320 + col];
    }
    #pragma unroll
    for (int i = 0; i < ROWS / 4; i++) {
        int r = rg + i * 4;
        int gr = rowBase + r;
        float s = bc[col];
        #pragma unroll
        for (int k = 0; k < DIM; k++) s = fmaf(xa[r][k], Wc[k * DIM + col], s);
        float u = b2a[col];
        #pragma unroll
        for (int m = 0; m < BOT; m++) u = fmaf(m0[r][m], p2a[m * DIM + col], u);
        float v = b2b[col];
        #pragma unroll
        for (int m = 0; m < BOT; m++) v = fmaf(m1[r][m], p2b[m * DIM + col], v);
        if (MODE == 0) {
            if (gr < n) {
                sums[0] += s; sums[1] += s * s;
                sums[2] += u; sums[3] += u * u;
                sums[4] += v; sums[5] += v * v;
            }
        } else {
            float r0 = fmaf(s, S0, T0) + fmaf(u, S1, T1) + fmaf(v, S2, T2);
            if (MODE == 2) r0 = fmaxf(r0, 0.f);
            if (gr < n) hout[(size_t)gr * DIM + col] = r0;
        }
    }

    if (MODE == 0) {
        #pragma unroll
        for (int j = 0; j < 6; j++) red[j][rg][col] = sums[j];
        __syncthreads();
        if (t < DIM) {
            #pragma unroll
            for (int j = 0; j < 6; j++) {
                float v = red[j][0][t] + red[j][1][t] + red[j][2][t] + red[j][3][t];
                partials[((size_t)blockIdx.x * 6 + j) * DIM + t] = v;
            }
        }
    }
}

// ---------------- parallel stats reduce + BN fold ----------------

__global__ __launch_bounds__(256) void reduce_fold_k(
    const float* __restrict__ partials, int nb, int n,
    const float* __restrict__ bn_g, const float* __restrict__ bn_b,
    const float* __restrict__ pg0, const float* __restrict__ pb0,
    const float* __restrict__ pg1, const float* __restrict__ pb1,
    const float* __restrict__ gating, int l, float* __restrict__ ST) {
    __shared__ double red[6][256];
    int col = blockIdx.x;
    int t = threadIdx.x;
    double acc[6] = {0, 0, 0, 0, 0, 0};
    for (int b = t; b < nb; b += 256) {
        const float* p = partials + (size_t)b * 6 * DIM + col;
        #pragma unroll
        for (int j = 0; j < 6; j++) acc[j] += (double)p[j * DIM];
    }
    #pragma unroll
    for (int j = 0; j < 6; j++) red[j][t] = acc[j];
    __syncthreads();
    for (int off = 128; off > 0; off >>= 1) {
        if (t < off) {
            #pragma unroll
            for (int j = 0; j < 6; j++) red[j][t] += red[j][t + off];
        }
        __syncthreads();
    }
    if (t < 3) {
        int stat = t;
        float mean = (float)(red[2 * stat][0] / (double)n);
        float var = (float)(red[2 * stat + 1][0] / (double)n) - mean * mean;
        float rstd = rsqrtf(fmaxf(var, 0.f) + BN_EPS);
        float g, bb, gate;
        if (stat == 0)      { g = bn_g[col]; bb = bn_b[col]; gate = 1.f; }
        else if (stat == 1) { g = pg0[col];  bb = pb0[col];  gate = gating[0 * NLAYERS + l]; }
        else                { g = pg1[col];  bb = pb1[col];  gate = gating[1 * NLAYERS + l]; }
        float S = g * rstd * gate;
        float T = (bb - mean * g * rstd) * gate;
        ST[stat * 128 + col] = S;
        ST[stat * 128 + 64 + col] = T;
    }
}

// ---------------- host ----------------

static inline char* bump(char*& p, size_t bytes) {
    char* r = p;
    p += (bytes + 255) & ~(size_t)255;
    return r;
}

extern "C" void kernel_launch(void* const* d_in, const int* in_sizes, int n_in,
                              void* d_out, int out_size, void* d_ws, size_t ws_size,
                              hipStream_t stream) {
    const float* x      = (const float*)d_in[0];
    const int*   ei     = (const int*)d_in[1];
    const float* W      = (const float*)d_in[2];
    const float* bconv  = (const float*)d_in[3];
    const float* bn_g   = (const float*)d_in[4];
    const float* bn_b   = (const float*)d_in[5];
    const float* pw1    = (const float*)d_in[6];
    const float* pb1    = (const float*)d_in[7];
    const float* pw2    = (const float*)d_in[8];
    const float* pb2    = (const float*)d_in[9];
    const float* pbn_g  = (const float*)d_in[10];
    const float* pbn_b  = (const float*)d_in[11];
    const float* gating = (const float*)d_in[12];

    int n = in_sizes[0] / DIM;
    int E = in_sizes[1] / 2;
    int nb = (n + ROWS - 1) / ROWS;
    int nb1024 = (n + 1023) / 1024;
    size_t n64b = (size_t)n * DIM * sizeof(float);

    // carve workspace
    char* p = (char*)d_ws;
    float* h_ws     = (float*)bump(p, n64b);
    float* partials = (float*)bump(p, (size_t)nb * 6 * DIM * sizeof(float));
    float* ST       = (float*)bump(p, 6 * 128 * sizeof(float));
    int*   bsum     = (int*)bump(p, (size_t)nb1024 * sizeof(int));
    int*   boff     = (int*)bump(p, (size_t)nb1024 * sizeof(int));
    int*   deg      = (int*)bump(p, (size_t)n * sizeof(int));
    int*   row_ptr  = (int*)bump(p, (size_t)(n + 1) * sizeof(int));
    int*   csr      = (int*)bump(p, (size_t)E * sizeof(int));
    // fast-path extras
    float* yv = (float*)bump(p, n64b);
    float* uv = (float*)bump(p, n64b);
    float* vv = (float*)bump(p, n64b);
    bool fast = ((size_t)(p - (char*)d_ws) <= ws_size);
    float* aggr = yv;  // fallback reuses yv slot (fits: checked against round-2 layout)

    const int* esrc = ei;
    const int* edst = ei + E;

    // CSR build
    hipMemsetAsync(deg, 0, (size_t)n * sizeof(int), stream);
    hist_k<<<(E + 255) / 256, 256, 0, stream>>>(edst, deg, E);
    scan_part_k<<<nb1024, 1024, 0, stream>>>(deg, row_ptr, bsum, n);
    scan_top_k<<<1, 1024, 0, stream>>>(bsum, boff, nb1024, row_ptr, n);
    scan_add_k<<<(n + 255) / 256, 256, 0, stream>>>(row_ptr, boff, deg, n);
    scatter_k<<<(E + 255) / 256, 256, 0, stream>>>(esrc, edst, deg, csr, E);

    for (int l = 0; l < NLAYERS; l++) {
        const float* Wl  = W     + (size_t)l * DIM * DIM;
        const float* bl  = bconv + (size_t)l * DIM;
        const float* bgl = bn_g  + (size_t)l * DIM;
        const float* bbl = bn_b  + (size_t)l * DIM;
        const float* p1a = pw1 + ((size_t)0 * NLAYERS + l) * DIM * BOT;
        const float* p1b = pw1 + ((size_t)1 * NLAYERS + l) * DIM * BOT;
        const float* b1a = pb1 + ((size_t)0 * NLAYERS + l) * BOT;
        const float* b1b = pb1 + ((size_t)1 * NLAYERS + l) * BOT;
        const float* p2a = pw2 + ((size_t)0 * NLAYERS + l) * BOT * DIM;
        const float* p2b = pw2 + ((size_t)1 * NLAYERS + l) * BOT * DIM;
        const float* b2a = pb2 + ((size_t)0 * NLAYERS + l) * DIM;
        const float* b2b = pb2 + ((size_t)1 * NLAYERS + l) * DIM;
        const float* g0  = pbn_g + ((size_t)0 * NLAYERS + l) * DIM;
        const float* g1  = pbn_g + ((size_t)1 * NLAYERS + l) * DIM;
        const float* be0 = pbn_b + ((size_t)0 * NLAYERS + l) * DIM;
        const float* be1 = pbn_b + ((size_t)1 * NLAYERS + l) * DIM;

        const float* hin = (l == 0) ? x : h_ws;

        if (fast) {
            fused_k<<<nb, THREADS, 0, stream>>>(
                hin, row_ptr, csr, Wl, bl, p1a, b1a, p2a, b2a,
                p1b, b1b, p2b, b2b, partials, yv, uv, vv, n);

            reduce_fold_k<<<DIM, 256, 0, stream>>>(partials, nb, n, bgl, bbl,
                                                   g0, be0, g1, be1, gating, l, ST);

            int n4 = n * (DIM / 4);
            float* outp = (l < NLAYERS - 1) ? h_ws : (float*)d_out;
            if (l < NLAYERS - 1)
                apply_k<1><<<(n4 + 255) / 256, 256, 0, stream>>>(yv, uv, vv, ST, outp, n4);
            else
                apply_k<0><<<(n4 + 255) / 256, 256, 0, stream>>>(yv, uv, vv, ST, outp, n4);
        } else {
            aggr_k<<<(n + 3) / 4, 256, 0, stream>>>(hin, row_ptr, csr, aggr, n);

            layer_k<0><<<nb, THREADS, 0, stream>>>(
                hin, aggr, Wl, bl, p1a, b1a, p2a, b2a, p1b, b1b, p2b, b2b,
                partials, nullptr, nullptr, n);

            reduce_fold_k<<<DIM, 256, 0, stream>>>(partials, nb, n, bgl, bbl,
                                                   g0, be0, g1, be1, gating, l, ST);

            if (l < NLAYERS - 1) {
                layer_k<2><<<nb, THREADS, 0, stream>>>(
                    hin, aggr, Wl, bl, p1a, b1a, p2a, b2a, p1b, b1b, p2b, b2b,
                    nullptr, ST, h_ws, n);
            } else {
                layer_k<1><<<nb, THREADS, 0, stream>>>(
                    hin, aggr, Wl, bl, p1a, b1a, p2a, b2a, p1b, b1b, p2b, b2b,
                    nullptr, ST, (float*)d_out, n);
            }
        }
    }
}